// Round 9
// baseline (331.449 us; speedup 1.0000x reference)
//
#include <hip/hip_runtime.h>
#include <hip/hip_bf16.h>
#include <stdint.h>

// Problem constants
#define BATCH 64
#define IN_CAPS 512          // In (input capsules)
#define NCAP 16              // num_capsule
#define DCAP 64              // dim_capsule
#define GN (NCAP * DCAP)     // 1024
#define GM (BATCH * IN_CAPS) // 32768
#define GK 768               // input feature dim (K)

typedef __bf16 bf16;
typedef __attribute__((ext_vector_type(8))) __bf16 bf16x8;
typedef __attribute__((ext_vector_type(4))) float f32x4;

// ===========================================================================
// ALGEBRAIC RESTRUCTURE (round 9): U = x@W is never materialized.
//   out_i = squash(W_i^T (sum_j c_ij x_j))     [y-path]
//   bl_j  = <W_i out_i, x_j> = <z_i, x_j>      [z-path]
// The 51.5-GFLOP GEMM + 64 MiB U buffer + U routing sweeps are all gone;
// replaced by thin per-b GEMMs (805 MFLOP/iter) on L3-resident Xb.
// ===========================================================================

// ---------------------------------------------------------------------------
// Kernel 1: X (fp32) -> bf16 convert + per-b row-sum partials (validated
// rounds 3-8).  Register accumulation, single LDS merge at the end.
// ---------------------------------------------------------------------------
__global__ __launch_bounds__(256) void k_convX2(const float* __restrict__ X,
                                                bf16* __restrict__ Xb,
                                                float* __restrict__ XS) {
    __shared__ float ls[GK];
    const int tid = threadIdx.x;
    ls[tid] = 0.f; ls[tid + 256] = 0.f; ls[tid + 512] = 0.f;
    __syncthreads();
    const size_t base = (size_t)blockIdx.x * (32 * GK);
    float acc[3][8] = {};  // static indices only (g = r%3 is compile-time)
#pragma unroll
    for (int r = 0; r < 12; ++r) {
        const int off = r * 2048 + tid * 8;  // 12*2048 = 24576 = 32*768
        const f32x4 a0 = *(const f32x4*)(X + base + off);
        const f32x4 a1 = *(const f32x4*)(X + base + off + 4);
        bf16x8 o;
        o[0] = (bf16)a0[0]; o[1] = (bf16)a0[1]; o[2] = (bf16)a0[2]; o[3] = (bf16)a0[3];
        o[4] = (bf16)a1[0]; o[5] = (bf16)a1[1]; o[6] = (bf16)a1[2]; o[7] = (bf16)a1[3];
        *(bf16x8*)(Xb + base + off) = o;
        const int g = r % 3;
        acc[g][0] += a0[0]; acc[g][1] += a0[1];
        acc[g][2] += a0[2]; acc[g][3] += a0[3];
        acc[g][4] += a1[0]; acc[g][5] += a1[1];
        acc[g][6] += a1[2]; acc[g][7] += a1[3];
    }
    if (XS != nullptr) {
#pragma unroll
        for (int g = 0; g < 3; ++g) {
            const int cg = (g == 1) ? 512 : (g == 2) ? 256 : 0;
            const int kb = (tid * 8 + cg) % GK;
#pragma unroll
            for (int j = 0; j < 8; ++j) atomicAdd(&ls[kb + j], acc[g][j]);
        }
        __syncthreads();
        const int bidx = blockIdx.x >> 4;
        atomicAdd(&XS[(size_t)bidx * GK + tid],       ls[tid]);
        atomicAdd(&XS[(size_t)bidx * GK + tid + 256], ls[tid + 256]);
        atomicAdd(&XS[(size_t)bidx * GK + tid + 512], ls[tid + 512]);
    }
}

// ---------------------------------------------------------------------------
// Kernel 2: transpose W [768][1024] fp32 -> Wt [1024][768] bf16 (K-contig).
// Also zeroes XS.  (validated)
// ---------------------------------------------------------------------------
__global__ void k_transW(const float* __restrict__ W, bf16* __restrict__ Wt,
                         float* __restrict__ XS) {
    __shared__ bf16 t[32][33];
    const int k0 = blockIdx.x * 32;
    const int n0 = blockIdx.y * 32;
    const int tx = threadIdx.x, ty = threadIdx.y;
    if (XS != nullptr) {
        const int gid = (blockIdx.y * gridDim.x + blockIdx.x) * 256 + ty * 32 + tx;
        if (gid < BATCH * GK) XS[gid] = 0.f;
    }
#pragma unroll
    for (int r = 0; r < 4; ++r)
        t[ty + r * 8][tx] = (bf16)W[(size_t)(k0 + ty + r * 8) * GN + n0 + tx];
    __syncthreads();
#pragma unroll
    for (int r = 0; r < 4; ++r)
        Wt[(size_t)(n0 + ty + r * 8) * GK + k0 + tx] = t[tx][ty + r * 8];
}

// ---------------------------------------------------------------------------
// Kernel 3: out1 = squash((1/16) xsum . W)  [validated rounds 3-8] and NEW:
// Z1[b,cap,k] = sum_d Wt[cap*64+d][k] * out1[d]  (coalesced k-contig Wt rows,
// broadcast out1 from LDS).  O1 no longer stored — only Z1 is consumed.
// Grid 256 = cap(16) x b-group(16, 4 b's each), 256 threads.
// ---------------------------------------------------------------------------
__global__ __launch_bounds__(256) void k_out1z(const float* __restrict__ XS,
                                               const float* __restrict__ W,
                                               const bf16* __restrict__ Wt,
                                               float* __restrict__ Z) {
    __shared__ float xs[4][GK];      // 12 KiB
    __shared__ float red[4][4][64];  // 4 KiB
    __shared__ float sout4[4][64];   // 1 KiB: out1 per bb
    const int cap = blockIdx.x & 15;
    const int bg = blockIdx.x >> 4;
    const int tid = threadIdx.x;
    const int k = tid & 63, kq = tid >> 6;
#pragma unroll
    for (int bb = 0; bb < 4; ++bb) {
        const size_t b = (size_t)(bg * 4 + bb);
        xs[bb][tid]       = XS[b * GK + tid];
        xs[bb][tid + 256] = XS[b * GK + tid + 256];
        xs[bb][tid + 512] = XS[b * GK + tid + 512];
    }
    __syncthreads();
    float acc4[4] = {0.f, 0.f, 0.f, 0.f};
    const float* wp = W + (size_t)(kq * 192) * GN + cap * 64 + k;
#pragma unroll 4
    for (int kk = 0; kk < 192; ++kk) {
        const float w = wp[(size_t)kk * GN];
        const int kx = kq * 192 + kk;
        acc4[0] += xs[0][kx] * w;
        acc4[1] += xs[1][kx] * w;
        acc4[2] += xs[2][kx] * w;
        acc4[3] += xs[3][kx] * w;
    }
#pragma unroll
    for (int bb = 0; bb < 4; ++bb) red[bb][kq][k] = acc4[bb];
    __syncthreads();
    if (tid < 64) {
#pragma unroll
        for (int bb = 0; bb < 4; ++bb) {
            float s = (red[bb][0][tid] + red[bb][1][tid] +
                       red[bb][2][tid] + red[bb][3][tid]) * 0.0625f;
            float ss = s * s;
#pragma unroll
            for (int off = 32; off >= 1; off >>= 1) ss += __shfl_xor(ss, off);
            sout4[bb][tid] = s * rsqrtf(ss + 1e-7f);
        }
    }
    __syncthreads();
    // Z1: coalesced Wt rows (k-contig across tid), out1 broadcast from LDS
#pragma unroll
    for (int bb = 0; bb < 4; ++bb) {
        const size_t bi = (size_t)(bg * 4 + bb) * NCAP + cap;
#pragma unroll
        for (int r = 0; r < 3; ++r) {
            const int kk = r * 256 + tid;
            float z = 0.f;
#pragma unroll 8
            for (int d = 0; d < 64; ++d)
                z += (float)Wt[(size_t)(cap * 64 + d) * GK + kk] * sout4[bb][d];
            Z[bi * GK + kk] = z;
        }
    }
}

// ---------------------------------------------------------------------------
// Kernel 4: BL[b,cap,j] = sum_k Z[b,cap,k] * Xb[b,j,k]  (MFMA).
// M=16 (caps), N=512 (j, split 4x128), K=768.  A = bf16(Z) staged in LDS
// row-major [16][768+pad] (gemm-validated A-frag convention); B = Xb rows
// read directly from global ([j][k-contig] is mfma's natural B layout).
// D mapping (validated): col=lane&15 -> j, row=(lane>>4)*4+r -> cap.
// Grid 256 = b(64) x jsplit(4); 4 waves each take 32 j.
// ---------------------------------------------------------------------------
__global__ __launch_bounds__(256) void k_bl(const float* __restrict__ Z,
                                            const bf16* __restrict__ Xb,
                                            float* __restrict__ BLo) {
    __shared__ __align__(16) bf16 za[16 * 776];  // pad 768->776: bank spread
    const int b  = blockIdx.x >> 2;
    const int js = blockIdx.x & 3;
    const int tid = threadIdx.x;
    const int lane = tid & 63;
    const int wave = tid >> 6;
    const int fr = lane & 15, fq = lane >> 4;

    // stage A = bf16(Z[b]) -> za[cap][k]
#pragma unroll
    for (int cap = 0; cap < 16; ++cap) {
        const float* zp = Z + ((size_t)b * NCAP + cap) * GK;
#pragma unroll
        for (int r = 0; r < 3; ++r) {
            const int kk = r * 256 + tid;
            za[cap * 776 + kk] = (bf16)zp[kk];
        }
    }
    __syncthreads();

    const int j0 = js * 128 + wave * 32;
    f32x4 acc[2] = {};
    for (int kt = 0; kt < GK / 32; ++kt) {
        const bf16x8 af = *(const bf16x8*)(za + fr * 776 + kt * 32 + fq * 8);
#pragma unroll
        for (int ni = 0; ni < 2; ++ni) {
            const bf16x8 bf = *(const bf16x8*)(
                Xb + ((size_t)b * IN_CAPS + j0 + ni * 16 + fr) * GK + kt * 32 + fq * 8);
            acc[ni] = __builtin_amdgcn_mfma_f32_16x16x32_bf16(af, bf, acc[ni], 0, 0, 0);
        }
    }
#pragma unroll
    for (int ni = 0; ni < 2; ++ni)
#pragma unroll
        for (int r = 0; r < 4; ++r) {
            const int cap = fq * 4 + r;
            const int j = j0 + ni * 16 + fr;
            BLo[((size_t)b * NCAP + cap) * IN_CAPS + j] = acc[ni][r];
        }
}

// ---------------------------------------------------------------------------
// Kernel 5: softmax over caps + partial y.  Block (b, js of 8): 64 j each.
//   c[j][cap] = softmax_cap(BL[b][cap][j])   (fp32 — better than bf16-c)
//   Yp[bid][cap][n] = sum_{j in slice} c[j][cap] * Xb[b][j][n]
// Thread owns n = {tid, tid+256, tid+512}; c read as 4x f32x4 LDS broadcast.
// ---------------------------------------------------------------------------
__global__ __launch_bounds__(256) void k_y(const float* __restrict__ BLi,
                                           const bf16* __restrict__ Xb,
                                           float* __restrict__ Yp) {
    __shared__ __align__(16) float sc[64][16];  // 4 KiB: c[j_local][cap]
    const int b  = blockIdx.x >> 3;
    const int js = blockIdx.x & 7;
    const int tid = threadIdx.x;
    if (tid < 64) {
        const int j = js * 64 + tid;
        const float* p = BLi + (size_t)b * NCAP * IN_CAPS + j;
        float v[16], mx = -1e30f;
#pragma unroll
        for (int i = 0; i < 16; ++i) { v[i] = p[(size_t)i * IN_CAPS]; mx = fmaxf(mx, v[i]); }
        float s = 0.f;
#pragma unroll
        for (int i = 0; i < 16; ++i) { v[i] = __expf(v[i] - mx); s += v[i]; }
        const float inv = 1.f / s;
#pragma unroll
        for (int i = 0; i < 16; ++i) sc[tid][i] = v[i] * inv;
    }
    __syncthreads();

    float acc[16][3] = {};  // all indices compile-time in unrolled loops
    for (int jl = 0; jl < 64; ++jl) {
        const bf16* xp = Xb + ((size_t)b * IN_CAPS + js * 64 + jl) * GK + tid;
        const float x0 = (float)xp[0];
        const float x1 = (float)xp[256];
        const float x2 = (float)xp[512];
        const f32x4 c0 = *(const f32x4*)(&sc[jl][0]);
        const f32x4 c1 = *(const f32x4*)(&sc[jl][4]);
        const f32x4 c2 = *(const f32x4*)(&sc[jl][8]);
        const f32x4 c3 = *(const f32x4*)(&sc[jl][12]);
#pragma unroll
        for (int i = 0; i < 4; ++i) {
            acc[i][0]      += c0[i] * x0; acc[i][1]      += c0[i] * x1; acc[i][2]      += c0[i] * x2;
            acc[4 + i][0]  += c1[i] * x0; acc[4 + i][1]  += c1[i] * x1; acc[4 + i][2]  += c1[i] * x2;
            acc[8 + i][0]  += c2[i] * x0; acc[8 + i][1]  += c2[i] * x1; acc[8 + i][2]  += c2[i] * x2;
            acc[12 + i][0] += c3[i] * x0; acc[12 + i][1] += c3[i] * x1; acc[12 + i][2] += c3[i] * x2;
        }
    }
#pragma unroll
    for (int cap = 0; cap < 16; ++cap) {
        float* yp = Yp + ((size_t)blockIdx.x * NCAP + cap) * GK;
        yp[tid] = acc[cap][0]; yp[tid + 256] = acc[cap][1]; yp[tid + 512] = acc[cap][2];
    }
}

// ---------------------------------------------------------------------------
// Kernel 6: reduce Yp -> y; out = squash(W^T y) (fp32 W, k_out1-validated
// strided pattern, coalesced across d-lanes); then either final OutC or
// Z_next[k] = sum_d Wt[cap*64+d][k]*out[d] (coalesced Wt rows).
// Grid 1024 = (b,cap), 256 threads.
// ---------------------------------------------------------------------------
__global__ __launch_bounds__(256) void k_oz(const float* __restrict__ Yp,
                                            const float* __restrict__ W,
                                            const bf16* __restrict__ Wt,
                                            float* __restrict__ Zo,
                                            float* __restrict__ OutC) {
    __shared__ float ly[GK];       // 3 KiB: y
    __shared__ float red[4][64];
    __shared__ float sout[64];
    const int bi = blockIdx.x;
    const int b = bi >> 4, cap = bi & 15;
    const int tid = threadIdx.x;
#pragma unroll
    for (int r = 0; r < 3; ++r) {
        const int kk = r * 256 + tid;
        float s = 0.f;
#pragma unroll
        for (int js = 0; js < 8; ++js)
            s += Yp[(((size_t)b * 8 + js) * NCAP + cap) * GK + kk];
        ly[kk] = s;
    }
    __syncthreads();
    const int d = tid & 63, kq = tid >> 6;
    {
        float a = 0.f;
        const float* wp = W + (size_t)(kq * 192) * GN + cap * 64 + d;
#pragma unroll 4
        for (int kk = 0; kk < 192; ++kk)
            a += ly[kq * 192 + kk] * wp[(size_t)kk * GN];
        red[kq][d] = a;
    }
    __syncthreads();
    if (tid < 64) {
        float s = red[0][tid] + red[1][tid] + red[2][tid] + red[3][tid];
        float ss = s * s;
#pragma unroll
        for (int off = 32; off >= 1; off >>= 1) ss += __shfl_xor(ss, off);
        const float val = s * rsqrtf(ss + 1e-7f);
        sout[tid] = val;
        if (OutC != nullptr) OutC[(size_t)bi * DCAP + tid] = val;
    }
    if (OutC != nullptr) return;
    __syncthreads();
#pragma unroll
    for (int r = 0; r < 3; ++r) {
        const int kk = r * 256 + tid;
        float z = 0.f;
#pragma unroll 8
        for (int dd = 0; dd < 64; ++dd)
            z += (float)Wt[(size_t)(cap * 64 + dd) * GK + kk] * sout[dd];
        Zo[(size_t)bi * GK + kk] = z;
    }
}

// ===========================================================================
// Fallback tier (old validated U-path) — only if ws can't hold the new set.
// ===========================================================================
__global__ __launch_bounds__(256) void k_gemm_inline(const float* __restrict__ X,
                                                     const bf16* __restrict__ Wt,
                                                     bf16* __restrict__ U) {
    __shared__ bf16 sA[128 * 32];
    __shared__ bf16 sB[128 * 32];
    const int tid = threadIdx.x;
    const int lane = tid & 63;
    const int wave = tid >> 6;
    const int wm = wave >> 1, wn = wave & 1;
    const int m0 = blockIdx.x * 128;
    const int n0 = blockIdx.y * 128;
    const int srow = tid >> 2;
    const int scol = (tid & 3) * 8;
    f32x4 acc[4][4] = {};
    const int fr = lane & 15;
    const int fq = lane >> 4;
    for (int kt = 0; kt < GK / 32; ++kt) {
        const int kb = kt * 32;
        bf16x8 a0, a1, b0, b1;
        {
            const float* p = X + (size_t)(m0 + srow) * GK + kb + scol;
            const f32x4 x0 = *(const f32x4*)p, x1 = *(const f32x4*)(p + 4);
            const float* q = X + (size_t)(m0 + srow + 64) * GK + kb + scol;
            const f32x4 y0 = *(const f32x4*)q, y1 = *(const f32x4*)(q + 4);
#pragma unroll
            for (int c = 0; c < 4; ++c) {
                a0[c] = (bf16)x0[c]; a0[c + 4] = (bf16)x1[c];
                a1[c] = (bf16)y0[c]; a1[c + 4] = (bf16)y1[c];
            }
        }
        b0 = *(const bf16x8*)(Wt + (size_t)(n0 + srow) * GK + kb + scol);
        b1 = *(const bf16x8*)(Wt + (size_t)(n0 + srow + 64) * GK + kb + scol);
        __syncthreads();
        *(bf16x8*)(sA + srow * 32 + scol) = a0;
        *(bf16x8*)(sA + (srow + 64) * 32 + scol) = a1;
        *(bf16x8*)(sB + srow * 32 + scol) = b0;
        *(bf16x8*)(sB + (srow + 64) * 32 + scol) = b1;
        __syncthreads();
        bf16x8 af[4], bfr[4];
#pragma unroll
        for (int mi = 0; mi < 4; ++mi)
            af[mi] = *(const bf16x8*)(sA + (wm * 64 + mi * 16 + fr) * 32 + fq * 8);
#pragma unroll
        for (int ni = 0; ni < 4; ++ni)
            bfr[ni] = *(const bf16x8*)(sB + (wn * 64 + ni * 16 + fr) * 32 + fq * 8);
#pragma unroll
        for (int mi = 0; mi < 4; ++mi)
#pragma unroll
            for (int ni = 0; ni < 4; ++ni)
                acc[mi][ni] = __builtin_amdgcn_mfma_f32_16x16x32_bf16(
                    af[mi], bfr[ni], acc[mi][ni], 0, 0, 0);
    }
#pragma unroll
    for (int mi = 0; mi < 4; ++mi) {
#pragma unroll
        for (int ni = 0; ni < 4; ++ni) {
#pragma unroll
            for (int r = 0; r < 4; ++r) {
                const int m = m0 + wm * 64 + mi * 16 + fq * 4 + r;
                const int n = n0 + wn * 64 + ni * 16 + fr;
                const int bb = m >> 9, j = m & 511;
                const int ci = n >> 6, k = n & 63;
                U[(((size_t)(bb * NCAP + ci)) * IN_CAPS + j) * DCAP + k] =
                    (bf16)acc[mi][ni][r];
            }
        }
    }
}

__global__ __launch_bounds__(256) void k_route(const bf16* __restrict__ U,
                                               const float* __restrict__ BLin,
                                               float* __restrict__ BLout,
                                               float* __restrict__ OutC,
                                               int mode) {
    __shared__ float sc[IN_CAPS];
    __shared__ float red2[4][64];
    __shared__ float sout[64];
    const int bi = blockIdx.x;
    const int b = bi >> 4, cap = bi & 15;
    const int tid = threadIdx.x;
    const int lane = tid & 63;
    const int wave = tid >> 6;
    const size_t ubase = (size_t)bi * IN_CAPS * DCAP;

    if (mode == 0) {
        sc[tid] = 0.0625f;
        sc[tid + 256] = 0.0625f;
    } else {
#pragma unroll
        for (int h = 0; h < 2; ++h) {
            const int j = tid + h * 256;
            const float* p = BLin + (size_t)b * NCAP * IN_CAPS + j;
            float v[16], mx = -1e30f;
#pragma unroll
            for (int i = 0; i < 16; ++i) {
                v[i] = p[(size_t)i * IN_CAPS];
                mx = fmaxf(mx, v[i]);
            }
            float s = 0.f;
#pragma unroll
            for (int i = 0; i < 16; ++i) s += __expf(v[i] - mx);
            sc[j] = __expf(v[cap] - mx) / s;
        }
    }
    __syncthreads();

    const int g = tid & 7;
    const int jr = tid >> 3;

    float acc[8] = {};
#pragma unroll
    for (int it = 0; it < 16; ++it) {
        const int j = it * 32 + jr;
        const bf16x8 v = *(const bf16x8*)(U + ubase + (size_t)it * 2048 + tid * 8);
        const float cv = sc[j];
#pragma unroll
        for (int c = 0; c < 8; ++c) acc[c] += cv * (float)v[c];
    }
#pragma unroll
    for (int c = 0; c < 8; ++c) {
        acc[c] += __shfl_xor(acc[c], 8);
        acc[c] += __shfl_xor(acc[c], 16);
        acc[c] += __shfl_xor(acc[c], 32);
    }
    if ((lane >> 3) == 0) {
#pragma unroll
        for (int c = 0; c < 8; ++c) red2[wave][lane * 8 + c] = acc[c];
    }
    __syncthreads();

    if (tid < 64) {
        float s = red2[0][tid] + red2[1][tid] + red2[2][tid] + red2[3][tid];
        float ss = s * s;
#pragma unroll
        for (int off = 32; off >= 1; off >>= 1) ss += __shfl_xor(ss, off);
        const float val = s * rsqrtf(ss + 1e-7f);
        sout[tid] = val;
        if (mode == 2) OutC[(size_t)bi * DCAP + tid] = val;
    }
    if (mode == 2) return;
    __syncthreads();

    const f32x4 o0 = *(const f32x4*)(sout + g * 8);
    const f32x4 o1 = *(const f32x4*)(sout + g * 8 + 4);
#pragma unroll
    for (int it = 0; it < 16; ++it) {
        const int j = it * 32 + jr;
        const bf16x8 v = *(const bf16x8*)(U + ubase + (size_t)it * 2048 + tid * 8);
        float p = o0[0] * (float)v[0] + o0[1] * (float)v[1] +
                  o0[2] * (float)v[2] + o0[3] * (float)v[3] +
                  o1[0] * (float)v[4] + o1[1] * (float)v[5] +
                  o1[2] * (float)v[6] + o1[3] * (float)v[7];
        p += __shfl_xor(p, 1);
        p += __shfl_xor(p, 2);
        p += __shfl_xor(p, 4);
        if (g == 0) BLout[((size_t)(b * NCAP + cap)) * IN_CAPS + j] = p;
    }
}

// ---------------------------------------------------------------------------
extern "C" void kernel_launch(void* const* d_in, const int* in_sizes, int n_in,
                              void* d_out, int out_size, void* d_ws, size_t ws_size,
                              hipStream_t stream) {
    const float* X = (const float*)d_in[0]; // [64][512][768] fp32
    const float* W = (const float*)d_in[1]; // [768][1024] fp32
    float* OutC = (float*)d_out;            // [64][16][64] fp32

    const size_t xb_bytes = (size_t)GM * GK * sizeof(bf16);                       // 48 MiB
    const size_t wt_bytes = (size_t)GN * GK * sizeof(bf16);                       // 1.5 MiB
    const size_t xs_bytes = (size_t)BATCH * GK * sizeof(float);                   // 192 KiB
    const size_t z_bytes  = (size_t)BATCH * NCAP * GK * sizeof(float);            // 3 MiB
    const size_t bl_bytes = (size_t)BATCH * NCAP * IN_CAPS * sizeof(float);       // 2 MiB
    const size_t yp_bytes = (size_t)BATCH * 8 * NCAP * GK * sizeof(float);        // 25.2 MiB
    char* ws = (char*)d_ws;

    const size_t need_new = xb_bytes + wt_bytes + xs_bytes + z_bytes + bl_bytes + yp_bytes;

    const size_t u_bytes = (size_t)BATCH * NCAP * IN_CAPS * DCAP * sizeof(bf16);  // 64 MiB
    const size_t need_old = u_bytes + wt_bytes + bl_bytes;

    if (ws_size >= need_new) {
        bf16* Xb  = (bf16*)ws;
        bf16* Wt  = (bf16*)(ws + xb_bytes);
        float* XS = (float*)(ws + xb_bytes + wt_bytes);
        float* Z  = (float*)(ws + xb_bytes + wt_bytes + xs_bytes);
        float* BL = (float*)(ws + xb_bytes + wt_bytes + xs_bytes + z_bytes);
        float* Yp = (float*)(ws + xb_bytes + wt_bytes + xs_bytes + z_bytes + bl_bytes);

        // prep: Wt (+XS zero), Xb (+XS row-sums)
        k_transW<<<dim3(GK / 32, GN / 32), dim3(32, 8), 0, stream>>>(W, Wt, XS);
        k_convX2<<<GM / 32, 256, 0, stream>>>(X, Xb, XS);
        // iter 1: out1 from row-sums, Z1 = W.out1
        k_out1z<<<256, 256, 0, stream>>>(XS, W, Wt, Z);
        // iter 2: BL1 = Z1.Xb^T ; c2 ; y2 ; out2 -> Z2
        k_bl<<<BATCH * 4, 256, 0, stream>>>(Z, Xb, BL);
        k_y<<<BATCH * 8, 256, 0, stream>>>(BL, Xb, Yp);
        k_oz<<<BATCH * NCAP, 256, 0, stream>>>(Yp, W, Wt, Z, nullptr);
        // iter 3: BL2 ; c3 ; y3 ; out3 -> OutC
        k_bl<<<BATCH * 4, 256, 0, stream>>>(Z, Xb, BL);
        k_y<<<BATCH * 8, 256, 0, stream>>>(BL, Xb, Yp);
        k_oz<<<BATCH * NCAP, 256, 0, stream>>>(Yp, W, Wt, nullptr, OutC);
    } else if (ws_size >= need_old) {
        bf16* U = (bf16*)ws;
        bf16* Wt = (bf16*)(ws + u_bytes);
        float* BL = (float*)(ws + u_bytes + wt_bytes);
        k_transW<<<dim3(GK / 32, GN / 32), dim3(32, 8), 0, stream>>>(W, Wt, nullptr);
        k_gemm_inline<<<dim3(GM / 128, GN / 128), 256, 0, stream>>>(X, Wt, U);
        k_route<<<BATCH * NCAP, 256, 0, stream>>>(U, BL, BL, OutC, 0);
        k_route<<<BATCH * NCAP, 256, 0, stream>>>(U, BL, BL, OutC, 1);
        k_route<<<BATCH * NCAP, 256, 0, stream>>>(U, BL, BL, OutC, 2);
    }
}